// Round 12
// baseline (175.509 us; speedup 1.0000x reference)
//
#include <hip/hip_runtime.h>
#include <cstdint>
#include <cstddef>

#define D_DIM   256
#define B_ROWS  1024
#define C_CLS   200000
#define S_SC    64.0f
#define COS_M_F 0.87758256189037271612f
#define SIN_M_F 0.47942553860420300027f
#define EPS_F   1e-8f

#define CT 256                     /* classes per block */
#define NCB 782                    /* 782*256 = 200192 class tiles = grid */
#define CPAD (NCB * CT)            /* 200192 */
#define NPADROW (CPAD - C_CLS)     /* 192 zero rows -> exp(0)=1 each */

typedef int   i32x4  __attribute__((ext_vector_type(4)));
typedef int   i32x8  __attribute__((ext_vector_type(8)));
typedef float f32x16 __attribute__((ext_vector_type(16)));

// ---------------- kernel 1: normalize {proto, emb} -> fp8 e4m3 ----------------
__global__ void k_norm_all8(const float* __restrict__ emb,
                            const float* __restrict__ proto,
                            unsigned char* __restrict__ ebf8,
                            unsigned char* __restrict__ pbf8) {
  int wid = threadIdx.x >> 6, lane = threadIdx.x & 63;
  int idx = (blockIdx.x << 2) + wid;
  const float* src;
  unsigned char* dst;
  if (idx < CPAD) {
    if (idx >= C_CLS) {
      *reinterpret_cast<unsigned int*>(pbf8 + (size_t)idx * D_DIM + lane * 4) = 0u;
      return;
    }
    src = proto + (size_t)idx * D_DIM;
    dst = pbf8 + (size_t)idx * D_DIM;
  } else {
    int row = idx - CPAD;
    src = emb + (size_t)row * D_DIM;
    dst = ebf8 + (size_t)row * D_DIM;
  }
  const float4 v = *reinterpret_cast<const float4*>(src + lane * 4);
  float ss = v.x * v.x + v.y * v.y + v.z * v.z + v.w * v.w;
#pragma unroll
  for (int m = 32; m >= 1; m >>= 1) ss += __shfl_xor(ss, m, 64);
  float inv = 1.0f / fmaxf(sqrtf(ss), 1e-12f);
  int packed = 0;
  packed = __builtin_amdgcn_cvt_pk_fp8_f32(v.x * inv, v.y * inv, packed, false);
  packed = __builtin_amdgcn_cvt_pk_fp8_f32(v.z * inv, v.w * inv, packed, true);
  *reinterpret_cast<int*>(dst + lane * 4) = packed;
}

// ------- kernel 2: register-resident MX-fp8 GEMM, batch-loop, in-lane exp -----
// Wave owns 64 classes x full K=256 in REGISTERS (af, loaded once: proto read
// = 51 MB total, the minimum). Loop over 32 batch strips: emb frags global->reg
// (L2-hot), 8 MFMA, in-lane exp-sum, one plain LDS store per strip (per-wave
// private bsum row: no atomics, no barriers, no K-path LDS).
__global__ __launch_bounds__(256, 3) void k_gemm_cls(
    const unsigned char* __restrict__ ebf8, const unsigned char* __restrict__ pbf8,
    float* __restrict__ sums) {
  __shared__ float bsum[4][B_ROWS];   // 16 KiB, per-wave private rows

  const int t = threadIdx.x;
  const int lane = t & 63;
  const int rsel = lane & 31;        // class-row (A) / batch-col (B) within 32
  const int h = lane >> 5;           // k-half of each 64-K window
  const int wv = t >> 6;             // wave 0..3

  const int c0 = (int)blockIdx.x * CT + wv * 64;

  // ---- prologue: A (proto) fragments global->reg, 64 VGPR ----
  i32x8 af[2][4];
  {
    const unsigned char* ab = pbf8 + (size_t)(c0 + rsel) * D_DIM + h * 32;
#pragma unroll
    for (int mi = 0; mi < 2; ++mi)
#pragma unroll
      for (int ks = 0; ks < 4; ++ks) {
        const unsigned char* p = ab + mi * (32 * D_DIM) + ks * 64;
        i32x4 lo = *reinterpret_cast<const i32x4*>(p);
        i32x4 hi = *reinterpret_cast<const i32x4*>(p + 16);
        af[mi][ks] = __builtin_shufflevector(lo, hi, 0, 1, 2, 3, 4, 5, 6, 7);
      }
  }

  // ---- batch loop: 32 strips of 32 ----
  const unsigned char* ebase = ebf8 + (size_t)rsel * D_DIM + h * 32;
#pragma unroll 1
  for (int s = 0; s < 32; ++s) {
    const unsigned char* eb = ebase + (size_t)s * (32 * D_DIM);
    i32x8 bf[4];
#pragma unroll
    for (int ks = 0; ks < 4; ++ks) {
      i32x4 lo = *reinterpret_cast<const i32x4*>(eb + ks * 64);
      i32x4 hi = *reinterpret_cast<const i32x4*>(eb + ks * 64 + 16);
      bf[ks] = __builtin_shufflevector(lo, hi, 0, 1, 2, 3, 4, 5, 6, 7);
    }
    f32x16 acc[2];
#pragma unroll
    for (int mi = 0; mi < 2; ++mi)
#pragma unroll
      for (int e = 0; e < 16; ++e) acc[mi][e] = 0.0f;
#pragma unroll
    for (int ks = 0; ks < 4; ++ks) {
#pragma unroll
      for (int mi = 0; mi < 2; ++mi)
        acc[mi] = __builtin_amdgcn_mfma_scale_f32_32x32x64_f8f6f4(
            af[mi][ks], bf[ks], acc[mi], 0, 0,   // cbsz=fp8, blgp=fp8
            0, 0x7F7F7F7F, 0, 0x7F7F7F7F);       // unit scales (E8M0=127)
    }
    // in-lane exp-sum over this lane's 32 class rows for batch col s*32+rsel
    float bp = 0.0f;
#pragma unroll
    for (int mi = 0; mi < 2; ++mi)
#pragma unroll
      for (int e = 0; e < 16; ++e)
        bp += __expf(S_SC * acc[mi][e]);
    bp += __shfl_xor(bp, 32, 64);    // combine the two k-half lane groups
    if (h == 0) bsum[wv][s * 32 + rsel] = bp;
  }

  // ---- block reduce: 4 wave rows -> global atomic ----
  __syncthreads();
#pragma unroll
  for (int j = 0; j < 4; ++j) {
    int col = t + j * 256;
    float v = bsum[0][col] + bsum[1][col] + bsum[2][col] + bsum[3][col];
    atomicAdd(&sums[col], v);
  }
}

// ---------------- kernel 3: label column + final loss -------------------------
__device__ __forceinline__ float f8tof(unsigned char u) {
  int e = (u >> 3) & 15, m = u & 7;
  float mag = e ? ldexpf((float)(8 + m), e - 10) : ldexpf((float)m, -9);
  return (u & 0x80) ? -mag : mag;
}

__global__ void k_finalize(const unsigned char* __restrict__ ebf8,
                           const unsigned char* __restrict__ pbf8,
                           const int* __restrict__ labels,
                           const float* __restrict__ sums,
                           float* __restrict__ out) {
  __shared__ float part[4];
  int wid = threadIdx.x >> 6, lane = threadIdx.x & 63;
  int b = (blockIdx.x << 2) + wid;
  int lab = labels[b];
  const unsigned char* e = ebf8 + (size_t)b * D_DIM + lane * 4;
  const unsigned char* p = pbf8 + (size_t)lab * D_DIM + lane * 4;
  unsigned int eu = *reinterpret_cast<const unsigned int*>(e);
  unsigned int pu = *reinterpret_cast<const unsigned int*>(p);
  float dot = 0.0f;
#pragma unroll
  for (int i = 0; i < 4; ++i)
    dot += f8tof((eu >> (8 * i)) & 0xff) * f8tof((pu >> (8 * i)) & 0xff);
#pragma unroll
  for (int m = 32; m >= 1; m >>= 1) dot += __shfl_xor(dot, m, 64);
  if (lane == 0) {
    float cs = dot;
    float sn = sqrtf(fmaxf(1.0f - cs * cs, EPS_F));
    sn = fminf(fmaxf(sn, EPS_F), 1.0f - EPS_F);
    float phi = cs * COS_M_F - sn * SIN_M_F;
    float sp = S_SC * phi;
    // subtract the 192 zero-pad rows' exp(0)=1 contributions
    float total = sums[b] - (float)NPADROW - __expf(S_SC * cs) + __expf(sp);
    part[wid] = logf(total) - sp;
  }
  __syncthreads();
  if (threadIdx.x == 0) {
    float s = part[0] + part[1] + part[2] + part[3];
    atomicAdd(out, s * (1.0f / (float)B_ROWS));
  }
}

// ---------------- launcher ----------------------------------------------------
extern "C" void kernel_launch(void* const* d_in, const int* in_sizes, int n_in,
                              void* d_out, int out_size, void* d_ws, size_t ws_size,
                              hipStream_t stream) {
  const float* emb    = (const float*)d_in[0];
  const int*   labels = (const int*)d_in[1];
  const float* proto  = (const float*)d_in[2];
  float* out = (float*)d_out;

  char* ws = (char*)d_ws;
  unsigned char* ebf8 = (unsigned char*)ws;                 // 262144 B
  float* sums = (float*)(ws + 262144);                      // 4096 B
  unsigned char* pbf8 = (unsigned char*)(ws + 2097152);     // CPAD*256 = 51.2 MB

  hipMemsetAsync(sums, 0, B_ROWS * sizeof(float), stream);
  hipMemsetAsync(out, 0, sizeof(float), stream);

  k_norm_all8<<<(CPAD + B_ROWS) / 4, 256, 0, stream>>>(emb, proto, ebf8, pbf8);
  k_gemm_cls<<<NCB, 256, 0, stream>>>(ebf8, pbf8, sums);
  k_finalize<<<B_ROWS / 4, 256, 0, stream>>>(ebf8, pbf8, labels, sums, out);
}